// Round 16
// baseline (158.722 us; speedup 1.0000x reference)
//
#include <hip/hip_runtime.h>
#include <math.h>

// MoE gate, round 16: staged-bytes reduction. R8-R15 established staging runs at
// ~10 B/cyc/CU (6.1 TB/s aggregate) regardless of structure -> time = staged
// bytes / 6.1 TB/s. BT=256 with K-split 4 (grid 256): B traffic 335->84 MB,
// total staged 469->218 MB. R13's plain-__syncthreads 2-buffer loop (best
// empirical). glog = 4 f32 partial planes; epi sums them. fixup/aux/pack as R15.

#define T_TOKENS 16384
#define HID      2048
#define NEXP     160
#define NGRP     8
#define EPG      20
#define KGRP     3
#define KTOP     6

#define BT     256               // tokens per gemm block
#define NKQ    4                 // K-split
#define KQLEN  512
#define NBODY  16                // K bodies of 32 within the quarter
#define ABY    32768             // A per body: 256 rows x 128 B
#define BBY    20480             // B per body
#define BUF    53248             // ABY + BBY
#define NEPI   256               // epi blocks (64 tokens each)
#define LPAD   68
#define PSTR   (256 * 160 * 64)  // glog plane stride (floats)

typedef __attribute__((ext_vector_type(8))) short short8;
typedef __attribute__((ext_vector_type(4))) float f32x4;
typedef __attribute__((ext_vector_type(4))) unsigned int uint4v;

union U4S8 { uint4v u; short8 s; float4 f; };

__device__ __forceinline__ unsigned short f2bf(float f) {
    unsigned u = __float_as_uint(f);
    return (unsigned short)((u + 0x7FFFu + ((u >> 16) & 1u)) >> 16);
}
__device__ __forceinline__ float bf2f(unsigned short s) {
    return __uint_as_float(((unsigned)s) << 16);
}
__device__ __forceinline__ unsigned cvtpk(float a, float b) {
    unsigned r;
    asm volatile("v_cvt_pk_bf16_f32 %0, %1, %2" : "=v"(r) : "v"(a), "v"(b));
    return r;
}
__device__ __forceinline__ float lo16(unsigned u) { return __uint_as_float(u << 16); }
__device__ __forceinline__ float hi16(unsigned u) { return __uint_as_float(u & 0xFFFF0000u); }

__device__ __forceinline__ void cp16(char* lds, const float* g) {
    __builtin_amdgcn_global_load_lds(
        (const __attribute__((address_space(1))) unsigned int*)g,
        (__attribute__((address_space(3))) unsigned int*)lds, 16, 0, 0);
}

// ---- pack W: [s=0..63][nt=0..9][plane hi/lo][lane][8] ------------------------
__global__ __launch_bounds__(256)
void pack_w(const float* __restrict__ W, short* __restrict__ wpk)
{
    const int idx = blockIdx.x * 256 + threadIdx.x;   // 160*256
    const int e  = idx >> 8;
    const int kc = idx & 255;
    const int k0 = kc * 8;
    const float* src = W + (size_t)e * HID + k0;
    float x[8];
    *(float4*)&x[0] = *(const float4*)src;
    *(float4*)&x[4] = *(const float4*)(src + 4);
    short8 h, l;
#pragma unroll
    for (int j = 0; j < 8; ++j) {
        unsigned short hb = f2bf(x[j]);
        h[j] = (short)hb;
        l[j] = (short)f2bf(x[j] - bf2f(hb));
    }
    const int s    = kc >> 2;            // 32-K step (global)
    const int kg   = kc & 3;
    const int lane = kg * 16 + (e & 15);
    const int nt   = e >> 4;
    const size_t base = (size_t)((s * 10 + nt) * 2) * 1024 + (size_t)lane * 16;
    *(short8*)((char*)wpk + base)        = h;
    *(short8*)((char*)wpk + base + 1024) = l;
}

// ---- GEMM: BT=256, K-quarter per block; partials -> glog[kq][tokblk][e][t64] --
__global__ __launch_bounds__(512, 1)
void moe_gemm(const float* __restrict__ X, const short* __restrict__ wpk,
              float* __restrict__ glog)
{
    __shared__ __align__(16) char smem[2 * BUF];   // 106496 B

    const int tid  = threadIdx.x;
    const int lane = tid & 63;
    const int wave = tid >> 6;
    const int tokgrp = wave >> 1;        // 0..3: 64-token group
    const int ns     = wave & 1;         // 0..1: 80-expert group
    const int tb = blockIdx.x >> 2;      // 0..63: token block of 256
    const int kq = blockIdx.x & 3;       // 0..3: K quarter
    const int tokBase = tb * BT;
    const char* wpkB = (const char*)wpk + (size_t)(kq * NBODY) * BBY;

    // A staging sources: 4 chunks/thread; idx=tid+j*512, r=idx>>3, c=idx&7,
    // LDS[idx*16] holds global chunk g=c^(r&7).  (dst = uniform + lane*16.)
    const float* srcA[4];
#pragma unroll
    for (int j = 0; j < 4; ++j) {
        const int idx = tid + j * 512;
        const int r = idx >> 3, c = idx & 7;
        srcA[j] = X + (size_t)(tokBase + r) * HID + kq * KQLEN + ((c ^ (r & 7)) << 2);
    }

    // fragment addresses
    const int lr = lane & 15;
    const int kg = lane >> 4;            // 0..3
    const int c0s = (((kg * 2    ) ^ (lr & 7)) << 4);
    const int c1s = (((kg * 2 + 1) ^ (lr & 7)) << 4);
    int rbase[4];
#pragma unroll
    for (int mt = 0; mt < 4; ++mt) rbase[mt] = (tokgrp * 64 + mt * 16 + lr) * 128;
    const int boff = ABY + ns * 10240 + lane * 16;

    f32x4 acc[4][5];
#pragma unroll
    for (int m = 0; m < 4; ++m)
#pragma unroll
        for (int n = 0; n < 5; ++n) acc[m][n] = (f32x4){0.f, 0.f, 0.f, 0.f};

#define STG(BI, S) { char* b_ = smem + (BI) * BUF;                               \
    _Pragma("unroll") for (int j = 0; j < 4; ++j)                                \
        cp16(b_ + (tid + j * 512) * 16, srcA[j] + (S) * 32);                     \
    cp16(b_ + ABY + tid * 16,                                                    \
         (const float*)(wpkB + (size_t)(S) * BBY + tid * 16));                   \
    cp16(b_ + ABY + (tid + 512) * 16,                                            \
         (const float*)(wpkB + (size_t)(S) * BBY + (tid + 512) * 16));           \
    if (tid < 256)                                                               \
        cp16(b_ + ABY + (tid + 1024) * 16,                                       \
             (const float*)(wpkB + (size_t)(S) * BBY + (tid + 1024) * 16)); }

    STG(0, 0)
    __syncthreads();

#pragma unroll 1
    for (int s = 0; s < NBODY; ++s) {
        if (s < NBODY - 1) STG((s + 1) & 1, s + 1)
        const char* ab = smem + (s & 1) * BUF;

#pragma unroll
        for (int mt = 0; mt < 4; ++mt) {
            U4S8 af0, af1, ah, al;
            af0.f = *(const float4*)(ab + rbase[mt] + c0s);
            af1.f = *(const float4*)(ab + rbase[mt] + c1s);
            unsigned ph0 = cvtpk(af0.f.x, af0.f.y), ph1 = cvtpk(af0.f.z, af0.f.w);
            unsigned ph2 = cvtpk(af1.f.x, af1.f.y), ph3 = cvtpk(af1.f.z, af1.f.w);
            float l0 = af0.f.x - lo16(ph0), l1 = af0.f.y - hi16(ph0);
            float l2 = af0.f.z - lo16(ph1), l3 = af0.f.w - hi16(ph1);
            float l4 = af1.f.x - lo16(ph2), l5 = af1.f.y - hi16(ph2);
            float l6 = af1.f.z - lo16(ph3), l7 = af1.f.w - hi16(ph3);
            ah.u[0] = ph0; ah.u[1] = ph1; ah.u[2] = ph2; ah.u[3] = ph3;
            al.u[0] = cvtpk(l0, l1); al.u[1] = cvtpk(l2, l3);
            al.u[2] = cvtpk(l4, l5); al.u[3] = cvtpk(l6, l7);

#pragma unroll
            for (int nt = 0; nt < 5; ++nt) {
                U4S8 bh, bl;
                bh.u = *(const uint4v*)(ab + boff + nt * 2048);
                bl.u = *(const uint4v*)(ab + boff + nt * 2048 + 1024);
                acc[mt][nt] = __builtin_amdgcn_mfma_f32_16x16x32_bf16(ah.s, bh.s, acc[mt][nt], 0, 0, 0);
                acc[mt][nt] = __builtin_amdgcn_mfma_f32_16x16x32_bf16(ah.s, bl.s, acc[mt][nt], 0, 0, 0);
                acc[mt][nt] = __builtin_amdgcn_mfma_f32_16x16x32_bf16(al.s, bh.s, acc[mt][nt], 0, 0, 0);
            }
        }
        __syncthreads();
    }
#undef STG

    // write partial plane: glog[kq][tb*4 + tokgrp][e][t64]
    float* gb = glog + ((size_t)kq * 256 + tb * 4 + tokgrp) * (NEXP * 64);
#pragma unroll
    for (int mt = 0; mt < 4; ++mt)
#pragma unroll
    for (int nt = 0; nt < 5; ++nt) {
        const int e = ns * 80 + nt * 16 + lr;
        *(f32x4*)(gb + e * 64 + mt * 16 + kg * 4) = acc[mt][nt];
    }
}

// ---- epilogue: sum 4 K-planes, selection + Pi/hist partials -------------------
__global__ __launch_bounds__(512, 2)
void moe_epi(const float* __restrict__ glog, float* __restrict__ out,
             float* __restrict__ piPart, unsigned int* __restrict__ histPart,
             unsigned int* __restrict__ flagCnt, unsigned int* __restrict__ flagList)
{
    __shared__ __align__(16) float pL[NEXP * LPAD];   // 43520 B
    __shared__ __align__(16) float m_arr[64];
    __shared__ __align__(16) float invd_arr[64];
    __shared__ unsigned histL[NEXP];

    const int tid  = threadIdx.x;
    const int lane = tid & 63;
    const int tokBase = blockIdx.x * 64;
    const float* gb = glog + (size_t)blockIdx.x * (NEXP * 64);

#pragma unroll
    for (int j = 0; j < 5; ++j) {
        const int i = tid + j * 512;
        const int e = i >> 4, t4 = (i & 15) << 2;
        const float* p = gb + e * 64 + t4;
        float4 v0 = *(const float4*)(p);
        float4 v1 = *(const float4*)(p + PSTR);
        float4 v2 = *(const float4*)(p + 2 * (size_t)PSTR);
        float4 v3 = *(const float4*)(p + 3 * (size_t)PSTR);
        float4 v;
        v.x = (v0.x + v1.x) + (v2.x + v3.x);
        v.y = (v0.y + v1.y) + (v2.y + v3.y);
        v.z = (v0.z + v1.z) + (v2.z + v3.z);
        v.w = (v0.w + v1.w) + (v2.w + v3.w);
        *(float4*)&pL[e * LPAD + t4] = v;
    }
    if (tid < NEXP) histL[tid] = 0;
    __syncthreads();

    {
        const int t  = tid >> 3;
        const int gl = tid & 7;
        const int lbase = lane & 0x38;

        float mg_ = pL[(gl * EPG) * LPAD + t];
#pragma unroll
        for (int j = 1; j < EPG; ++j) mg_ = fmaxf(mg_, pL[(gl * EPG + j) * LPAD + t]);

        float gv[8];
#pragma unroll
        for (int gi = 0; gi < 8; ++gi) gv[gi] = __shfl(mg_, lbase + gi);

        float best = -1e30f; int bi = 0;
#pragma unroll
        for (int gi = 0; gi < NGRP; ++gi) if (gv[gi] > best) { best = gv[gi]; bi = gi; }
        const int sel0 = bi; int gmask = 1 << bi;
        best = -1e30f; bi = 0;
#pragma unroll
        for (int gi = 0; gi < NGRP; ++gi)
            if (!((gmask >> gi) & 1) && gv[gi] > best) { best = gv[gi]; bi = gi; }
        const int sel1 = bi; gmask |= 1 << bi;
        best = -1e30f; bi = 0;
#pragma unroll
        for (int gi = 0; gi < NGRP; ++gi)
            if (!((gmask >> gi) & 1) && gv[gi] > best) { best = gv[gi]; bi = gi; }
        const int sel2 = bi; gmask |= 1 << bi;
        const float g3v = best;
        float g4v = -1e30f;
#pragma unroll
        for (int gi = 0; gi < NGRP; ++gi)
            if (!((gmask >> gi) & 1)) g4v = fmaxf(g4v, gv[gi]);
        float mall = gv[0];
#pragma unroll
        for (int gi = 1; gi < NGRP; ++gi) mall = fmaxf(mall, gv[gi]);

        float dsum = 0.f;
#pragma unroll
        for (int j = 0; j < EPG; ++j)
            dsum += expf(pL[(gl * EPG + j) * LPAD + t] - mall);
        dsum += __shfl_xor(dsum, 1);
        dsum += __shfl_xor(dsum, 2);
        dsum += __shfl_xor(dsum, 4);
        const float invd = 1.0f / dsum;

        float cvv[8]; int ce[8];
#pragma unroll
        for (int c = 0; c < 8; ++c) {
            const int i = gl + 8 * c;
            if (i < 60) {
                const int sgrp = (i >= 40) ? sel2 : ((i >= 20) ? sel1 : sel0);
                const int e = sgrp * EPG + (i - ((i >= 40) ? 40 : ((i >= 20) ? 20 : 0)));
                ce[c] = e;
                cvv[c] = pL[e * LPAD + t];
            } else { ce[c] = 999; cvv[c] = -1e30f; }
        }

        int ch0, ch1, ch2, ch3, ch4, ch5;
        float cv0, cv1, cv2, cv3, cv4, cv5, cv6;
#pragma unroll
        for (int p = 0; p < 7; ++p) {
            float bv = -1e30f; int be = 999;
#pragma unroll
            for (int c = 0; c < 8; ++c)
                if (cvv[c] > bv || (cvv[c] == bv && ce[c] < be)) { bv = cvv[c]; be = ce[c]; }
#pragma unroll
            for (int off = 1; off < 8; off <<= 1) {
                const float ov = __shfl_xor(bv, off);
                const int   oe = __shfl_xor(be, off);
                if (ov > bv || (ov == bv && oe < be)) { bv = ov; be = oe; }
            }
#pragma unroll
            for (int c = 0; c < 8; ++c) if (ce[c] == be) cvv[c] = -1e30f;
            if (p == 0) { ch0 = be; cv0 = bv; }
            else if (p == 1) { ch1 = be; cv1 = bv; }
            else if (p == 2) { ch2 = be; cv2 = bv; }
            else if (p == 3) { ch3 = be; cv3 = bv; }
            else if (p == 4) { ch4 = be; cv4 = bv; }
            else if (p == 5) { ch5 = be; cv5 = bv; }
            else { cv6 = bv; }
        }

        if (gl == 0) {
            const int gt = tokBase + t;
            out[(size_t)gt * KTOP + 0] = (float)ch0;
            out[(size_t)gt * KTOP + 1] = (float)ch1;
            out[(size_t)gt * KTOP + 2] = (float)ch2;
            out[(size_t)gt * KTOP + 3] = (float)ch3;
            out[(size_t)gt * KTOP + 4] = (float)ch4;
            out[(size_t)gt * KTOP + 5] = (float)ch5;
            float* wo = out + (size_t)T_TOKENS * KTOP + (size_t)gt * KTOP;
            wo[0] = expf(cv0 - mall) * invd * 16.0f;
            wo[1] = expf(cv1 - mall) * invd * 16.0f;
            wo[2] = expf(cv2 - mall) * invd * 16.0f;
            wo[3] = expf(cv3 - mall) * invd * 16.0f;
            wo[4] = expf(cv4 - mall) * invd * 16.0f;
            wo[5] = expf(cv5 - mall) * invd * 16.0f;
            atomicAdd(&histL[ch0], 1u); atomicAdd(&histL[ch1], 1u);
            atomicAdd(&histL[ch2], 1u); atomicAdd(&histL[ch3], 1u);
            atomicAdd(&histL[ch4], 1u); atomicAdd(&histL[ch5], 1u);
            m_arr[t] = mall; invd_arr[t] = invd;
            float mg2 = g3v - g4v;
            mg2 = fminf(mg2, cv0 - cv1); mg2 = fminf(mg2, cv1 - cv2);
            mg2 = fminf(mg2, cv2 - cv3); mg2 = fminf(mg2, cv3 - cv4);
            mg2 = fminf(mg2, cv4 - cv5); mg2 = fminf(mg2, cv5 - cv6);
            if (mg2 < 1e-4f) {
                const unsigned pos = atomicAdd(flagCnt, 1u);
                flagList[pos] = (unsigned)gt;
            }
        }
    }
    __syncthreads();

    if (tid < NEXP) {
        const float* Le = pL + tid * LPAD;
        float s = 0.f;
#pragma unroll 4
        for (int t0 = 0; t0 < 64; t0 += 4) {
            const float4 lv = *(const float4*)(Le + t0);
            const float4 mv = *(const float4*)(m_arr + t0);
            const float4 iv = *(const float4*)(invd_arr + t0);
            s += expf(lv.x - mv.x) * iv.x;
            s += expf(lv.y - mv.y) * iv.y;
            s += expf(lv.z - mv.z) * iv.z;
            s += expf(lv.w - mv.w) * iv.w;
        }
        piPart[(size_t)tid * NEPI + blockIdx.x]   = s;
        histPart[(size_t)tid * NEPI + blockIdx.x] = histL[tid];
    }
}

// ---- fp64 fixup: 16 waves/block, hoisted loads, 10 experts/wave ---------------
__global__ __launch_bounds__(1024)
void moe_gate_fixup(const float* __restrict__ X, const float* __restrict__ W,
                    float* __restrict__ out, const unsigned int* __restrict__ flagCnt,
                    const unsigned int* __restrict__ flagList)
{
    __shared__ float xs[HID];
    __shared__ double ld[NEXP];
    const int nflag = (int)*flagCnt;
    const int tid = threadIdx.x;
    const int wv = tid >> 6, ln = tid & 63;   // 16 waves

    for (int i = blockIdx.x; i < nflag; i += gridDim.x) {
        const int t = (int)flagList[i];
        __syncthreads();
        for (int k = tid; k < HID / 4; k += 1024)
            ((float4*)xs)[k] = ((const float4*)(X + (size_t)t * HID))[k];
        __syncthreads();

#pragma unroll 1
        for (int e = wv; e < NEXP; e += 16) {
            const float* wr = W + (size_t)e * HID + ln * 4;
            const float* xp = xs + ln * 4;
            float4 w4[8];
#pragma unroll
            for (int j = 0; j < 8; ++j) w4[j] = *(const float4*)(wr + j * 256);
            double a0 = 0.0, a1 = 0.0;
#pragma unroll
            for (int j = 0; j < 8; ++j) {
                a0 = fma((double)xp[j * 256 + 0], (double)w4[j].x, a0);
                a1 = fma((double)xp[j * 256 + 1], (double)w4[j].y, a1);
                a0 = fma((double)xp[j * 256 + 2], (double)w4[j].z, a0);
                a1 = fma((double)xp[j * 256 + 3], (double)w4[j].w, a1);
            }
            double a = a0 + a1;
#pragma unroll
            for (int off = 32; off > 0; off >>= 1) a += __shfl_down(a, off);
            if (ln == 0) ld[e] = a;
        }
        __syncthreads();

        if (tid == 0) {
            double g[NGRP];
#pragma unroll
            for (int gi = 0; gi < NGRP; ++gi) {
                double mx = ld[gi * EPG];
                for (int j = 1; j < EPG; ++j) {
                    const double v = ld[gi * EPG + j];
                    if (v > mx) mx = v;
                }
                g[gi] = mx;
            }
            int gmask = 0;
#pragma unroll
            for (int p = 0; p < KGRP; ++p) {
                double best = -1.0e300; int bi = 0;
#pragma unroll
                for (int gi = 0; gi < NGRP; ++gi)
                    if (!((gmask >> gi) & 1) && g[gi] > best) { best = g[gi]; bi = gi; }
                gmask |= 1 << bi;
            }
            double mall = g[0];
#pragma unroll
            for (int gi = 1; gi < NGRP; ++gi) if (g[gi] > mall) mall = g[gi];
            float denom = 0.f;
            for (int e = 0; e < NEXP; ++e)
                denom += expf((float)(ld[e] - mall));
            const float invd = 1.0f / denom;

            int ch[KTOP];
            for (int p = 0; p < KTOP; ++p) {
                double best = -1.0e300; int bi = 0;
                for (int e = 0; e < NEXP; ++e) {
                    if (!((gmask >> (e / EPG)) & 1)) continue;
                    bool used = false;
#pragma unroll
                    for (int q = 0; q < KTOP; ++q)
                        if (q < p && ch[q] == e) used = true;
                    if (!used && ld[e] > best) { best = ld[e]; bi = e; }
                }
                ch[p] = bi;
                out[(size_t)t * KTOP + p] = (float)bi;
                out[(size_t)T_TOKENS * KTOP + (size_t)t * KTOP + p] =
                    expf((float)(best - mall)) * invd * 16.0f;
            }
        }
        __syncthreads();
    }
}

// ---- aux loss: reduce partials ----------------------------------------------
__global__ __launch_bounds__(256)
void moe_gate_aux(const float* __restrict__ piPart,
                  const unsigned int* __restrict__ histPart,
                  float* __restrict__ out)
{
    __shared__ double buf[NEXP];
    const int tid = threadIdx.x;
    if (tid < NEXP) {
        const float* pp = piPart + (size_t)tid * NEPI;
        const unsigned int* hp = histPart + (size_t)tid * NEPI;
        float s = 0.f;
        unsigned c = 0;
#pragma unroll 8
        for (int b = 0; b < NEPI; ++b) { s += pp[b]; c += hp[b]; }
        buf[tid] = (double)s * (double)c;
    }
    __syncthreads();
    if (tid == 0) {
        double s = 0.0;
        for (int e = 0; e < NEXP; ++e) s += buf[e];
        const double aux = s * (0.001 * (double)NEXP) /
                           ((double)T_TOKENS * (double)T_TOKENS * (double)KTOP);
        out[(size_t)T_TOKENS * KTOP * 2] = (float)aux;
    }
}

extern "C" void kernel_launch(void* const* d_in, const int* in_sizes, int n_in,
                              void* d_out, int out_size, void* d_ws, size_t ws_size,
                              hipStream_t stream)
{
    const float* X = (const float*)d_in[0];   // [16384, 2048]
    const float* W = (const float*)d_in[1];   // [160, 2048]
    float* out = (float*)d_out;               // [98304 idx][98304 wgt][1 aux]

    char* ws = (char*)d_ws;
    short* wpk = (short*)ws;                                    // 1,310,720 B
    float* glog = (float*)(ws + 1310720);                       // 4 planes x 10.49 MB = 41,943,040 B
    float* piPart = (float*)(ws + 43253760);                    // 163,840 B
    unsigned int* histPart = (unsigned int*)(ws + 43417600);    // 163,840 B
    unsigned int* flagCnt  = (unsigned int*)(ws + 43581440);    // 16 B
    unsigned int* flagList = (unsigned int*)(ws + 43581456);    // 64 KB

    hipMemsetAsync(flagCnt, 0, 16, stream);
    pack_w<<<160, 256, 0, stream>>>(W, wpk);
    moe_gemm<<<256, 512, 0, stream>>>(X, wpk, glog);
    moe_epi<<<NEPI, 512, 0, stream>>>(glog, out, piPart, histPart, flagCnt, flagList);
    moe_gate_fixup<<<512, 1024, 0, stream>>>(X, W, out, flagCnt, flagList);
    moe_gate_aux<<<1, 256, 0, stream>>>(piPart, histPart, out);
}

// Round 17
// 111.999 us; speedup vs baseline: 1.4172x; 1.4172x over previous
//
#include <hip/hip_runtime.h>
#include <math.h>

// MoE gate, round 17: identical to round 16 EXCEPT moe_gate_fixup's selection is
// wave-parallel (fp64 port of the epi selection). R16 showed fixup=83us was ONE
// token's serial tid==0 selection (~960 dependent LDS loads + 160 serial expf);
// nflag is ~hundreds (FETCH 5.3MB = X rows + 1.25MB W), blocks run 1 token each.

#define T_TOKENS 16384
#define HID      2048
#define NEXP     160
#define NGRP     8
#define EPG      20
#define KGRP     3
#define KTOP     6

#define BT     256               // tokens per gemm block
#define NKQ    4                 // K-split
#define KQLEN  512
#define NBODY  16                // K bodies of 32 within the quarter
#define ABY    32768             // A per body: 256 rows x 128 B
#define BBY    20480             // B per body
#define BUF    53248             // ABY + BBY
#define NEPI   256               // epi blocks (64 tokens each)
#define LPAD   68
#define PSTR   (256 * 160 * 64)  // glog plane stride (floats)

typedef __attribute__((ext_vector_type(8))) short short8;
typedef __attribute__((ext_vector_type(4))) float f32x4;
typedef __attribute__((ext_vector_type(4))) unsigned int uint4v;

union U4S8 { uint4v u; short8 s; float4 f; };

__device__ __forceinline__ unsigned short f2bf(float f) {
    unsigned u = __float_as_uint(f);
    return (unsigned short)((u + 0x7FFFu + ((u >> 16) & 1u)) >> 16);
}
__device__ __forceinline__ float bf2f(unsigned short s) {
    return __uint_as_float(((unsigned)s) << 16);
}
__device__ __forceinline__ unsigned cvtpk(float a, float b) {
    unsigned r;
    asm volatile("v_cvt_pk_bf16_f32 %0, %1, %2" : "=v"(r) : "v"(a), "v"(b));
    return r;
}
__device__ __forceinline__ float lo16(unsigned u) { return __uint_as_float(u << 16); }
__device__ __forceinline__ float hi16(unsigned u) { return __uint_as_float(u & 0xFFFF0000u); }

__device__ __forceinline__ void cp16(char* lds, const float* g) {
    __builtin_amdgcn_global_load_lds(
        (const __attribute__((address_space(1))) unsigned int*)g,
        (__attribute__((address_space(3))) unsigned int*)lds, 16, 0, 0);
}

// ---- pack W: [s=0..63][nt=0..9][plane hi/lo][lane][8] ------------------------
__global__ __launch_bounds__(256)
void pack_w(const float* __restrict__ W, short* __restrict__ wpk)
{
    const int idx = blockIdx.x * 256 + threadIdx.x;   // 160*256
    const int e  = idx >> 8;
    const int kc = idx & 255;
    const int k0 = kc * 8;
    const float* src = W + (size_t)e * HID + k0;
    float x[8];
    *(float4*)&x[0] = *(const float4*)src;
    *(float4*)&x[4] = *(const float4*)(src + 4);
    short8 h, l;
#pragma unroll
    for (int j = 0; j < 8; ++j) {
        unsigned short hb = f2bf(x[j]);
        h[j] = (short)hb;
        l[j] = (short)f2bf(x[j] - bf2f(hb));
    }
    const int s    = kc >> 2;            // 32-K step (global)
    const int kg   = kc & 3;
    const int lane = kg * 16 + (e & 15);
    const int nt   = e >> 4;
    const size_t base = (size_t)((s * 10 + nt) * 2) * 1024 + (size_t)lane * 16;
    *(short8*)((char*)wpk + base)        = h;
    *(short8*)((char*)wpk + base + 1024) = l;
}

// ---- GEMM: BT=256, K-quarter per block; partials -> glog[kq][tokblk][e][t64] --
__global__ __launch_bounds__(512, 1)
void moe_gemm(const float* __restrict__ X, const short* __restrict__ wpk,
              float* __restrict__ glog)
{
    __shared__ __align__(16) char smem[2 * BUF];   // 106496 B

    const int tid  = threadIdx.x;
    const int lane = tid & 63;
    const int wave = tid >> 6;
    const int tokgrp = wave >> 1;        // 0..3: 64-token group
    const int ns     = wave & 1;         // 0..1: 80-expert group
    const int tb = blockIdx.x >> 2;      // 0..63: token block of 256
    const int kq = blockIdx.x & 3;       // 0..3: K quarter
    const int tokBase = tb * BT;
    const char* wpkB = (const char*)wpk + (size_t)(kq * NBODY) * BBY;

    const float* srcA[4];
#pragma unroll
    for (int j = 0; j < 4; ++j) {
        const int idx = tid + j * 512;
        const int r = idx >> 3, c = idx & 7;
        srcA[j] = X + (size_t)(tokBase + r) * HID + kq * KQLEN + ((c ^ (r & 7)) << 2);
    }

    const int lr = lane & 15;
    const int kg = lane >> 4;            // 0..3
    const int c0s = (((kg * 2    ) ^ (lr & 7)) << 4);
    const int c1s = (((kg * 2 + 1) ^ (lr & 7)) << 4);
    int rbase[4];
#pragma unroll
    for (int mt = 0; mt < 4; ++mt) rbase[mt] = (tokgrp * 64 + mt * 16 + lr) * 128;
    const int boff = ABY + ns * 10240 + lane * 16;

    f32x4 acc[4][5];
#pragma unroll
    for (int m = 0; m < 4; ++m)
#pragma unroll
        for (int n = 0; n < 5; ++n) acc[m][n] = (f32x4){0.f, 0.f, 0.f, 0.f};

#define STG(BI, S) { char* b_ = smem + (BI) * BUF;                               \
    _Pragma("unroll") for (int j = 0; j < 4; ++j)                                \
        cp16(b_ + (tid + j * 512) * 16, srcA[j] + (S) * 32);                     \
    cp16(b_ + ABY + tid * 16,                                                    \
         (const float*)(wpkB + (size_t)(S) * BBY + tid * 16));                   \
    cp16(b_ + ABY + (tid + 512) * 16,                                            \
         (const float*)(wpkB + (size_t)(S) * BBY + (tid + 512) * 16));           \
    if (tid < 256)                                                               \
        cp16(b_ + ABY + (tid + 1024) * 16,                                       \
             (const float*)(wpkB + (size_t)(S) * BBY + (tid + 1024) * 16)); }

    STG(0, 0)
    __syncthreads();

#pragma unroll 1
    for (int s = 0; s < NBODY; ++s) {
        if (s < NBODY - 1) STG((s + 1) & 1, s + 1)
        const char* ab = smem + (s & 1) * BUF;

#pragma unroll
        for (int mt = 0; mt < 4; ++mt) {
            U4S8 af0, af1, ah, al;
            af0.f = *(const float4*)(ab + rbase[mt] + c0s);
            af1.f = *(const float4*)(ab + rbase[mt] + c1s);
            unsigned ph0 = cvtpk(af0.f.x, af0.f.y), ph1 = cvtpk(af0.f.z, af0.f.w);
            unsigned ph2 = cvtpk(af1.f.x, af1.f.y), ph3 = cvtpk(af1.f.z, af1.f.w);
            float l0 = af0.f.x - lo16(ph0), l1 = af0.f.y - hi16(ph0);
            float l2 = af0.f.z - lo16(ph1), l3 = af0.f.w - hi16(ph1);
            float l4 = af1.f.x - lo16(ph2), l5 = af1.f.y - hi16(ph2);
            float l6 = af1.f.z - lo16(ph3), l7 = af1.f.w - hi16(ph3);
            ah.u[0] = ph0; ah.u[1] = ph1; ah.u[2] = ph2; ah.u[3] = ph3;
            al.u[0] = cvtpk(l0, l1); al.u[1] = cvtpk(l2, l3);
            al.u[2] = cvtpk(l4, l5); al.u[3] = cvtpk(l6, l7);

#pragma unroll
            for (int nt = 0; nt < 5; ++nt) {
                U4S8 bh, bl;
                bh.u = *(const uint4v*)(ab + boff + nt * 2048);
                bl.u = *(const uint4v*)(ab + boff + nt * 2048 + 1024);
                acc[mt][nt] = __builtin_amdgcn_mfma_f32_16x16x32_bf16(ah.s, bh.s, acc[mt][nt], 0, 0, 0);
                acc[mt][nt] = __builtin_amdgcn_mfma_f32_16x16x32_bf16(ah.s, bl.s, acc[mt][nt], 0, 0, 0);
                acc[mt][nt] = __builtin_amdgcn_mfma_f32_16x16x32_bf16(al.s, bh.s, acc[mt][nt], 0, 0, 0);
            }
        }
        __syncthreads();
    }
#undef STG

    float* gb = glog + ((size_t)kq * 256 + tb * 4 + tokgrp) * (NEXP * 64);
#pragma unroll
    for (int mt = 0; mt < 4; ++mt)
#pragma unroll
    for (int nt = 0; nt < 5; ++nt) {
        const int e = ns * 80 + nt * 16 + lr;
        *(f32x4*)(gb + e * 64 + mt * 16 + kg * 4) = acc[mt][nt];
    }
}

// ---- epilogue: sum 4 K-planes, selection + Pi/hist partials -------------------
__global__ __launch_bounds__(512, 2)
void moe_epi(const float* __restrict__ glog, float* __restrict__ out,
             float* __restrict__ piPart, unsigned int* __restrict__ histPart,
             unsigned int* __restrict__ flagCnt, unsigned int* __restrict__ flagList)
{
    __shared__ __align__(16) float pL[NEXP * LPAD];   // 43520 B
    __shared__ __align__(16) float m_arr[64];
    __shared__ __align__(16) float invd_arr[64];
    __shared__ unsigned histL[NEXP];

    const int tid  = threadIdx.x;
    const int lane = tid & 63;
    const int tokBase = blockIdx.x * 64;
    const float* gb = glog + (size_t)blockIdx.x * (NEXP * 64);

#pragma unroll
    for (int j = 0; j < 5; ++j) {
        const int i = tid + j * 512;
        const int e = i >> 4, t4 = (i & 15) << 2;
        const float* p = gb + e * 64 + t4;
        float4 v0 = *(const float4*)(p);
        float4 v1 = *(const float4*)(p + PSTR);
        float4 v2 = *(const float4*)(p + 2 * (size_t)PSTR);
        float4 v3 = *(const float4*)(p + 3 * (size_t)PSTR);
        float4 v;
        v.x = (v0.x + v1.x) + (v2.x + v3.x);
        v.y = (v0.y + v1.y) + (v2.y + v3.y);
        v.z = (v0.z + v1.z) + (v2.z + v3.z);
        v.w = (v0.w + v1.w) + (v2.w + v3.w);
        *(float4*)&pL[e * LPAD + t4] = v;
    }
    if (tid < NEXP) histL[tid] = 0;
    __syncthreads();

    {
        const int t  = tid >> 3;
        const int gl = tid & 7;
        const int lbase = lane & 0x38;

        float mg_ = pL[(gl * EPG) * LPAD + t];
#pragma unroll
        for (int j = 1; j < EPG; ++j) mg_ = fmaxf(mg_, pL[(gl * EPG + j) * LPAD + t]);

        float gv[8];
#pragma unroll
        for (int gi = 0; gi < 8; ++gi) gv[gi] = __shfl(mg_, lbase + gi);

        float best = -1e30f; int bi = 0;
#pragma unroll
        for (int gi = 0; gi < NGRP; ++gi) if (gv[gi] > best) { best = gv[gi]; bi = gi; }
        const int sel0 = bi; int gmask = 1 << bi;
        best = -1e30f; bi = 0;
#pragma unroll
        for (int gi = 0; gi < NGRP; ++gi)
            if (!((gmask >> gi) & 1) && gv[gi] > best) { best = gv[gi]; bi = gi; }
        const int sel1 = bi; gmask |= 1 << bi;
        best = -1e30f; bi = 0;
#pragma unroll
        for (int gi = 0; gi < NGRP; ++gi)
            if (!((gmask >> gi) & 1) && gv[gi] > best) { best = gv[gi]; bi = gi; }
        const int sel2 = bi; gmask |= 1 << bi;
        const float g3v = best;
        float g4v = -1e30f;
#pragma unroll
        for (int gi = 0; gi < NGRP; ++gi)
            if (!((gmask >> gi) & 1)) g4v = fmaxf(g4v, gv[gi]);
        float mall = gv[0];
#pragma unroll
        for (int gi = 1; gi < NGRP; ++gi) mall = fmaxf(mall, gv[gi]);

        float dsum = 0.f;
#pragma unroll
        for (int j = 0; j < EPG; ++j)
            dsum += expf(pL[(gl * EPG + j) * LPAD + t] - mall);
        dsum += __shfl_xor(dsum, 1);
        dsum += __shfl_xor(dsum, 2);
        dsum += __shfl_xor(dsum, 4);
        const float invd = 1.0f / dsum;

        float cvv[8]; int ce[8];
#pragma unroll
        for (int c = 0; c < 8; ++c) {
            const int i = gl + 8 * c;
            if (i < 60) {
                const int sgrp = (i >= 40) ? sel2 : ((i >= 20) ? sel1 : sel0);
                const int e = sgrp * EPG + (i - ((i >= 40) ? 40 : ((i >= 20) ? 20 : 0)));
                ce[c] = e;
                cvv[c] = pL[e * LPAD + t];
            } else { ce[c] = 999; cvv[c] = -1e30f; }
        }

        int ch0, ch1, ch2, ch3, ch4, ch5;
        float cv0, cv1, cv2, cv3, cv4, cv5, cv6;
#pragma unroll
        for (int p = 0; p < 7; ++p) {
            float bv = -1e30f; int be = 999;
#pragma unroll
            for (int c = 0; c < 8; ++c)
                if (cvv[c] > bv || (cvv[c] == bv && ce[c] < be)) { bv = cvv[c]; be = ce[c]; }
#pragma unroll
            for (int off = 1; off < 8; off <<= 1) {
                const float ov = __shfl_xor(bv, off);
                const int   oe = __shfl_xor(be, off);
                if (ov > bv || (ov == bv && oe < be)) { bv = ov; be = oe; }
            }
#pragma unroll
            for (int c = 0; c < 8; ++c) if (ce[c] == be) cvv[c] = -1e30f;
            if (p == 0) { ch0 = be; cv0 = bv; }
            else if (p == 1) { ch1 = be; cv1 = bv; }
            else if (p == 2) { ch2 = be; cv2 = bv; }
            else if (p == 3) { ch3 = be; cv3 = bv; }
            else if (p == 4) { ch4 = be; cv4 = bv; }
            else if (p == 5) { ch5 = be; cv5 = bv; }
            else { cv6 = bv; }
        }

        if (gl == 0) {
            const int gt = tokBase + t;
            out[(size_t)gt * KTOP + 0] = (float)ch0;
            out[(size_t)gt * KTOP + 1] = (float)ch1;
            out[(size_t)gt * KTOP + 2] = (float)ch2;
            out[(size_t)gt * KTOP + 3] = (float)ch3;
            out[(size_t)gt * KTOP + 4] = (float)ch4;
            out[(size_t)gt * KTOP + 5] = (float)ch5;
            float* wo = out + (size_t)T_TOKENS * KTOP + (size_t)gt * KTOP;
            wo[0] = expf(cv0 - mall) * invd * 16.0f;
            wo[1] = expf(cv1 - mall) * invd * 16.0f;
            wo[2] = expf(cv2 - mall) * invd * 16.0f;
            wo[3] = expf(cv3 - mall) * invd * 16.0f;
            wo[4] = expf(cv4 - mall) * invd * 16.0f;
            wo[5] = expf(cv5 - mall) * invd * 16.0f;
            atomicAdd(&histL[ch0], 1u); atomicAdd(&histL[ch1], 1u);
            atomicAdd(&histL[ch2], 1u); atomicAdd(&histL[ch3], 1u);
            atomicAdd(&histL[ch4], 1u); atomicAdd(&histL[ch5], 1u);
            m_arr[t] = mall; invd_arr[t] = invd;
            float mg2 = g3v - g4v;
            mg2 = fminf(mg2, cv0 - cv1); mg2 = fminf(mg2, cv1 - cv2);
            mg2 = fminf(mg2, cv2 - cv3); mg2 = fminf(mg2, cv3 - cv4);
            mg2 = fminf(mg2, cv4 - cv5); mg2 = fminf(mg2, cv5 - cv6);
            if (mg2 < 1e-4f) {
                const unsigned pos = atomicAdd(flagCnt, 1u);
                flagList[pos] = (unsigned)gt;
            }
        }
    }
    __syncthreads();

    if (tid < NEXP) {
        const float* Le = pL + tid * LPAD;
        float s = 0.f;
#pragma unroll 4
        for (int t0 = 0; t0 < 64; t0 += 4) {
            const float4 lv = *(const float4*)(Le + t0);
            const float4 mv = *(const float4*)(m_arr + t0);
            const float4 iv = *(const float4*)(invd_arr + t0);
            s += expf(lv.x - mv.x) * iv.x;
            s += expf(lv.y - mv.y) * iv.y;
            s += expf(lv.z - mv.z) * iv.z;
            s += expf(lv.w - mv.w) * iv.w;
        }
        piPart[(size_t)tid * NEPI + blockIdx.x]   = s;
        histPart[(size_t)tid * NEPI + blockIdx.x] = histL[tid];
    }
}

// ---- fp64 fixup: parallel dots + WAVE-PARALLEL fp64 selection -----------------
__global__ __launch_bounds__(1024)
void moe_gate_fixup(const float* __restrict__ X, const float* __restrict__ W,
                    float* __restrict__ out, const unsigned int* __restrict__ flagCnt,
                    const unsigned int* __restrict__ flagList)
{
    __shared__ float xs[HID];
    __shared__ double ld[NEXP];
    const int nflag = (int)*flagCnt;
    const int tid = threadIdx.x;
    const int wv = tid >> 6, ln = tid & 63;   // 16 waves

    for (int i = blockIdx.x; i < nflag; i += gridDim.x) {
        const int t = (int)flagList[i];
        __syncthreads();
        for (int k = tid; k < HID / 4; k += 1024)
            ((float4*)xs)[k] = ((const float4*)(X + (size_t)t * HID))[k];
        __syncthreads();

#pragma unroll 1
        for (int e = wv; e < NEXP; e += 16) {
            const float* wr = W + (size_t)e * HID + ln * 4;
            const float* xp = xs + ln * 4;
            float4 w4[8];
#pragma unroll
            for (int j = 0; j < 8; ++j) w4[j] = *(const float4*)(wr + j * 256);
            double a0 = 0.0, a1 = 0.0;
#pragma unroll
            for (int j = 0; j < 8; ++j) {
                a0 = fma((double)xp[j * 256 + 0], (double)w4[j].x, a0);
                a1 = fma((double)xp[j * 256 + 1], (double)w4[j].y, a1);
                a0 = fma((double)xp[j * 256 + 2], (double)w4[j].z, a0);
                a1 = fma((double)xp[j * 256 + 3], (double)w4[j].w, a1);
            }
            double a = a0 + a1;
#pragma unroll
            for (int off = 32; off > 0; off >>= 1) a += __shfl_down(a, off);
            if (ln == 0) ld[e] = a;
        }
        __syncthreads();

        // ---- wave-parallel fp64 selection (wave 0; 8-lane group semantics) ----
        if (wv == 0) {
            const int gl = ln & 7;
            const int lbase = ln & 0x38;

            double gm = ld[gl * EPG];
#pragma unroll
            for (int j = 1; j < EPG; ++j) {
                const double v = ld[gl * EPG + j];
                if (v > gm) gm = v;
            }
            double gv[8];
#pragma unroll
            for (int gi = 0; gi < 8; ++gi) gv[gi] = __shfl(gm, lbase + gi);

            double best = -1.0e300; int bi = 0;
#pragma unroll
            for (int gi = 0; gi < NGRP; ++gi)
                if (gv[gi] > best) { best = gv[gi]; bi = gi; }
            const int sel0 = bi; int gmask = 1 << bi;
            best = -1.0e300; bi = 0;
#pragma unroll
            for (int gi = 0; gi < NGRP; ++gi)
                if (!((gmask >> gi) & 1) && gv[gi] > best) { best = gv[gi]; bi = gi; }
            const int sel1 = bi; gmask |= 1 << bi;
            best = -1.0e300; bi = 0;
#pragma unroll
            for (int gi = 0; gi < NGRP; ++gi)
                if (!((gmask >> gi) & 1) && gv[gi] > best) { best = gv[gi]; bi = gi; }
            const int sel2 = bi; gmask |= 1 << bi;
            double mall = gv[0];
#pragma unroll
            for (int gi = 1; gi < NGRP; ++gi) if (gv[gi] > mall) mall = gv[gi];

            float dsum = 0.f;
#pragma unroll
            for (int j = 0; j < EPG; ++j)
                dsum += expf((float)(ld[gl * EPG + j] - mall));
            dsum += __shfl_xor(dsum, 1);
            dsum += __shfl_xor(dsum, 2);
            dsum += __shfl_xor(dsum, 4);
            const float invd = 1.0f / dsum;

            double cvv[8]; int ce[8];
#pragma unroll
            for (int c = 0; c < 8; ++c) {
                const int idx = gl + 8 * c;
                if (idx < 60) {
                    const int sgrp = (idx >= 40) ? sel2 : ((idx >= 20) ? sel1 : sel0);
                    const int e = sgrp * EPG + (idx - ((idx >= 40) ? 40 : ((idx >= 20) ? 20 : 0)));
                    ce[c] = e;
                    cvv[c] = ld[e];
                } else { ce[c] = 999; cvv[c] = -1.0e300; }
            }

#pragma unroll
            for (int p = 0; p < KTOP; ++p) {
                double bv = -1.0e300; int be = 999;
#pragma unroll
                for (int c = 0; c < 8; ++c)
                    if (cvv[c] > bv || (cvv[c] == bv && ce[c] < be)) { bv = cvv[c]; be = ce[c]; }
#pragma unroll
                for (int off = 1; off < 8; off <<= 1) {
                    const double ov = __shfl_xor(bv, off);
                    const int    oe = __shfl_xor(be, off);
                    if (ov > bv || (ov == bv && oe < be)) { bv = ov; be = oe; }
                }
#pragma unroll
                for (int c = 0; c < 8; ++c) if (ce[c] == be) cvv[c] = -1.0e300;
                if (ln == 0) {
                    out[(size_t)t * KTOP + p] = (float)be;
                    out[(size_t)T_TOKENS * KTOP + (size_t)t * KTOP + p] =
                        expf((float)(bv - mall)) * invd * 16.0f;
                }
            }
        }
        __syncthreads();
    }
}

// ---- aux loss: reduce partials ----------------------------------------------
__global__ __launch_bounds__(256)
void moe_gate_aux(const float* __restrict__ piPart,
                  const unsigned int* __restrict__ histPart,
                  float* __restrict__ out)
{
    __shared__ double buf[NEXP];
    const int tid = threadIdx.x;
    if (tid < NEXP) {
        const float* pp = piPart + (size_t)tid * NEPI;
        const unsigned int* hp = histPart + (size_t)tid * NEPI;
        float s = 0.f;
        unsigned c = 0;
#pragma unroll 8
        for (int b = 0; b < NEPI; ++b) { s += pp[b]; c += hp[b]; }
        buf[tid] = (double)s * (double)c;
    }
    __syncthreads();
    if (tid == 0) {
        double s = 0.0;
        for (int e = 0; e < NEXP; ++e) s += buf[e];
        const double aux = s * (0.001 * (double)NEXP) /
                           ((double)T_TOKENS * (double)T_TOKENS * (double)KTOP);
        out[(size_t)T_TOKENS * KTOP * 2] = (float)aux;
    }
}

extern "C" void kernel_launch(void* const* d_in, const int* in_sizes, int n_in,
                              void* d_out, int out_size, void* d_ws, size_t ws_size,
                              hipStream_t stream)
{
    const float* X = (const float*)d_in[0];   // [16384, 2048]
    const float* W = (const float*)d_in[1];   // [160, 2048]
    float* out = (float*)d_out;               // [98304 idx][98304 wgt][1 aux]

    char* ws = (char*)d_ws;
    short* wpk = (short*)ws;                                    // 1,310,720 B
    float* glog = (float*)(ws + 1310720);                       // 41,943,040 B
    float* piPart = (float*)(ws + 43253760);                    // 163,840 B
    unsigned int* histPart = (unsigned int*)(ws + 43417600);    // 163,840 B
    unsigned int* flagCnt  = (unsigned int*)(ws + 43581440);    // 16 B
    unsigned int* flagList = (unsigned int*)(ws + 43581456);    // 64 KB

    hipMemsetAsync(flagCnt, 0, 16, stream);
    pack_w<<<160, 256, 0, stream>>>(W, wpk);
    moe_gemm<<<256, 512, 0, stream>>>(X, wpk, glog);
    moe_epi<<<NEPI, 512, 0, stream>>>(glog, out, piPart, histPart, flagCnt, flagList);
    moe_gate_fixup<<<512, 1024, 0, stream>>>(X, W, out, flagCnt, flagList);
    moe_gate_aux<<<1, 256, 0, stream>>>(piPart, histPart, out);
}

// Round 18
// 105.155 us; speedup vs baseline: 1.5094x; 1.0651x over previous
//
#include <hip/hip_runtime.h>
#include <math.h>

// MoE gate, round 18: gemm with A-only LDS staging (32 KB dbuf -> 2 blocks/CU)
// and B loaded L2->registers per body (wpk is L2-resident; 10 dwordx4/wave/body).
// R17 analysis: X is L3-resident (FETCH ~70MB), gemm was staging-instruction/
// drain bound at 1 block/CU. BT=128, NKQ=4, grid 512. Load order B(s) then
// A(s+1) so compiler's in-order vmcnt leaves A staging in flight during MFMA.

#define T_TOKENS 16384
#define HID      2048
#define NEXP     160
#define NGRP     8
#define EPG      20
#define KGRP     3
#define KTOP     6

#define BT     128               // tokens per gemm block
#define NKQ    4
#define KQLEN  512
#define NBODY  16                // bodies of BK=32
#define ABY    16384             // A per body: 128 rows x 128 B
#define NEPI   256
#define LPAD   68
#define PSTR   (512 * 160 * 32)  // glog plane stride (floats)

typedef __attribute__((ext_vector_type(8))) short short8;
typedef __attribute__((ext_vector_type(4))) float f32x4;
typedef __attribute__((ext_vector_type(4))) unsigned int uint4v;

union U4S8 { uint4v u; short8 s; float4 f; };

__device__ __forceinline__ unsigned short f2bf(float f) {
    unsigned u = __float_as_uint(f);
    return (unsigned short)((u + 0x7FFFu + ((u >> 16) & 1u)) >> 16);
}
__device__ __forceinline__ float bf2f(unsigned short s) {
    return __uint_as_float(((unsigned)s) << 16);
}
__device__ __forceinline__ unsigned cvtpk(float a, float b) {
    unsigned r;
    asm volatile("v_cvt_pk_bf16_f32 %0, %1, %2" : "=v"(r) : "v"(a), "v"(b));
    return r;
}
__device__ __forceinline__ float lo16(unsigned u) { return __uint_as_float(u << 16); }
__device__ __forceinline__ float hi16(unsigned u) { return __uint_as_float(u & 0xFFFF0000u); }

__device__ __forceinline__ void cp16(char* lds, const float* g) {
    __builtin_amdgcn_global_load_lds(
        (const __attribute__((address_space(1))) unsigned int*)g,
        (__attribute__((address_space(3))) unsigned int*)lds, 16, 0, 0);
}

// ---- pack W: [s=0..63][nt=0..9][plane hi/lo][lane][8]; also zero flagCnt ------
__global__ __launch_bounds__(256)
void pack_w(const float* __restrict__ W, short* __restrict__ wpk,
            unsigned int* __restrict__ flagCnt)
{
    if (blockIdx.x == 0 && threadIdx.x == 0) flagCnt[0] = 0;
    const int idx = blockIdx.x * 256 + threadIdx.x;   // 160*256
    const int e  = idx >> 8;
    const int kc = idx & 255;
    const int k0 = kc * 8;
    const float* src = W + (size_t)e * HID + k0;
    float x[8];
    *(float4*)&x[0] = *(const float4*)src;
    *(float4*)&x[4] = *(const float4*)(src + 4);
    short8 h, l;
#pragma unroll
    for (int j = 0; j < 8; ++j) {
        unsigned short hb = f2bf(x[j]);
        h[j] = (short)hb;
        l[j] = (short)f2bf(x[j] - bf2f(hb));
    }
    const int s    = kc >> 2;            // 32-K body (global)
    const int kg   = kc & 3;
    const int lane = kg * 16 + (e & 15);
    const int nt   = e >> 4;
    const size_t base = (size_t)((s * 10 + nt) * 2) * 1024 + (size_t)lane * 16;
    *(short8*)((char*)wpk + base)        = h;
    *(short8*)((char*)wpk + base + 1024) = l;
}

// ---- GEMM: A-only LDS, B L2->reg; partials -> glog[kq][tile32][e][t32] --------
__global__ __launch_bounds__(512, 4)
void moe_gemm(const float* __restrict__ X, const short* __restrict__ wpk,
              float* __restrict__ glog)
{
    __shared__ __align__(16) char smem[2 * ABY];   // 32768 B

    const int tid  = threadIdx.x;
    const int lane = tid & 63;
    const int wave = tid >> 6;
    const int tokgrp = wave >> 1;        // 0..3: 32-token group
    const int ns     = wave & 1;         // 0..1: 80-expert group
    const int tb = blockIdx.x >> 2;      // 0..127
    const int kq = blockIdx.x & 3;
    const int tokBase = tb * BT;

    // A staging: 2 chunks/thread. idx=tid+j*512, r=idx>>3, c=idx&7;
    // LDS chunk holds global chunk c^(r&7).
    const float* srcA[2];
#pragma unroll
    for (int j = 0; j < 2; ++j) {
        const int idx = tid + j * 512;
        const int r = idx >> 3, c = idx & 7;
        srcA[j] = X + (size_t)(tokBase + r) * HID + kq * KQLEN + ((c ^ (r & 7)) << 2);
    }

    // fragment addresses
    const int lr = lane & 15;
    const int kg = lane >> 4;            // 0..3
    const int c0s = (((kg * 2    ) ^ (lr & 7)) << 4);
    const int c1s = (((kg * 2 + 1) ^ (lr & 7)) << 4);
    int rb[2];
#pragma unroll
    for (int mt = 0; mt < 2; ++mt) rb[mt] = (tokgrp * 32 + mt * 16 + lr) * 128;
    // B fragment base for this wave (body s: + s*20480; nt: + nt*2048; lo: +1024)
    const char* wb = (const char*)wpk
                   + ((size_t)(kq * NBODY) * 10 + ns * 5) * 2048 + (size_t)lane * 16;

    f32x4 acc[2][5];
#pragma unroll
    for (int m = 0; m < 2; ++m)
#pragma unroll
        for (int n = 0; n < 5; ++n) acc[m][n] = (f32x4){0.f, 0.f, 0.f, 0.f};

#define STGA(BI, S) { char* b_ = smem + (BI) * ABY;                          \
    cp16(b_ + tid * 16,         srcA[0] + (S) * 32);                         \
    cp16(b_ + (tid + 512) * 16, srcA[1] + (S) * 32); }

    STGA(0, 0)
    __syncthreads();

#pragma unroll 1
    for (int s = 0; s < NBODY; ++s) {
        // B(s) -> regs FIRST (so vmcnt-wait for B leaves A(s+1) in flight)
        U4S8 bh[5], bl[5];
        const char* wbs = wb + (size_t)s * 20480;
#pragma unroll
        for (int nt = 0; nt < 5; ++nt) {
            bh[nt].u = *(const uint4v*)(wbs + nt * 2048);
            bl[nt].u = *(const uint4v*)(wbs + nt * 2048 + 1024);
        }
        if (s < NBODY - 1) STGA((s + 1) & 1, s + 1)

        const char* ab = smem + (s & 1) * ABY;
#pragma unroll
        for (int mt = 0; mt < 2; ++mt) {
            U4S8 af0, af1, ah, al;
            af0.f = *(const float4*)(ab + rb[mt] + c0s);
            af1.f = *(const float4*)(ab + rb[mt] + c1s);
            unsigned ph0 = cvtpk(af0.f.x, af0.f.y), ph1 = cvtpk(af0.f.z, af0.f.w);
            unsigned ph2 = cvtpk(af1.f.x, af1.f.y), ph3 = cvtpk(af1.f.z, af1.f.w);
            float l0 = af0.f.x - lo16(ph0), l1 = af0.f.y - hi16(ph0);
            float l2 = af0.f.z - lo16(ph1), l3 = af0.f.w - hi16(ph1);
            float l4 = af1.f.x - lo16(ph2), l5 = af1.f.y - hi16(ph2);
            float l6 = af1.f.z - lo16(ph3), l7 = af1.f.w - hi16(ph3);
            ah.u[0] = ph0; ah.u[1] = ph1; ah.u[2] = ph2; ah.u[3] = ph3;
            al.u[0] = cvtpk(l0, l1); al.u[1] = cvtpk(l2, l3);
            al.u[2] = cvtpk(l4, l5); al.u[3] = cvtpk(l6, l7);

#pragma unroll
            for (int nt = 0; nt < 5; ++nt) {
                acc[mt][nt] = __builtin_amdgcn_mfma_f32_16x16x32_bf16(ah.s, bh[nt].s, acc[mt][nt], 0, 0, 0);
                acc[mt][nt] = __builtin_amdgcn_mfma_f32_16x16x32_bf16(ah.s, bl[nt].s, acc[mt][nt], 0, 0, 0);
                acc[mt][nt] = __builtin_amdgcn_mfma_f32_16x16x32_bf16(al.s, bh[nt].s, acc[mt][nt], 0, 0, 0);
            }
        }
        __syncthreads();
    }
#undef STGA

    // write partial tiles: glog[kq][tb*4+tokgrp][e][t32]
    float* gb = glog + (size_t)kq * PSTR + (size_t)(tb * 4 + tokgrp) * (NEXP * 32);
#pragma unroll
    for (int mt = 0; mt < 2; ++mt)
#pragma unroll
    for (int nt = 0; nt < 5; ++nt) {
        const int e = ns * 80 + nt * 16 + lr;
        *(f32x4*)(gb + e * 32 + mt * 16 + kg * 4) = acc[mt][nt];
    }
}

// ---- epilogue: sum 4 K-planes (32-token tiles), selection + Pi/hist -----------
__global__ __launch_bounds__(512, 2)
void moe_epi(const float* __restrict__ glog, float* __restrict__ out,
             float* __restrict__ piPart, unsigned int* __restrict__ histPart,
             unsigned int* __restrict__ flagCnt, unsigned int* __restrict__ flagList)
{
    __shared__ __align__(16) float pL[NEXP * LPAD];   // 43520 B
    __shared__ __align__(16) float m_arr[64];
    __shared__ __align__(16) float invd_arr[64];
    __shared__ unsigned histL[NEXP];

    const int tid  = threadIdx.x;
    const int lane = tid & 63;
    const int tokBase = blockIdx.x * 64;

#pragma unroll
    for (int j = 0; j < 5; ++j) {
        const int i = tid + j * 512;          // 0..2559
        const int e = i >> 4;
        const int q = (i & 15) << 2;          // 0..60
        const int tt = 2 * blockIdx.x + (q >> 5);
        const int off = q & 31;
        const float* p = glog + (size_t)tt * (NEXP * 32) + e * 32 + off;
        float4 v0 = *(const float4*)(p);
        float4 v1 = *(const float4*)(p + PSTR);
        float4 v2 = *(const float4*)(p + 2 * (size_t)PSTR);
        float4 v3 = *(const float4*)(p + 3 * (size_t)PSTR);
        float4 v;
        v.x = (v0.x + v1.x) + (v2.x + v3.x);
        v.y = (v0.y + v1.y) + (v2.y + v3.y);
        v.z = (v0.z + v1.z) + (v2.z + v3.z);
        v.w = (v0.w + v1.w) + (v2.w + v3.w);
        *(float4*)&pL[e * LPAD + q] = v;
    }
    if (tid < NEXP) histL[tid] = 0;
    __syncthreads();

    {
        const int t  = tid >> 3;
        const int gl = tid & 7;
        const int lbase = lane & 0x38;

        float mg_ = pL[(gl * EPG) * LPAD + t];
#pragma unroll
        for (int j = 1; j < EPG; ++j) mg_ = fmaxf(mg_, pL[(gl * EPG + j) * LPAD + t]);

        float gv[8];
#pragma unroll
        for (int gi = 0; gi < 8; ++gi) gv[gi] = __shfl(mg_, lbase + gi);

        float best = -1e30f; int bi = 0;
#pragma unroll
        for (int gi = 0; gi < NGRP; ++gi) if (gv[gi] > best) { best = gv[gi]; bi = gi; }
        const int sel0 = bi; int gmask = 1 << bi;
        best = -1e30f; bi = 0;
#pragma unroll
        for (int gi = 0; gi < NGRP; ++gi)
            if (!((gmask >> gi) & 1) && gv[gi] > best) { best = gv[gi]; bi = gi; }
        const int sel1 = bi; gmask |= 1 << bi;
        best = -1e30f; bi = 0;
#pragma unroll
        for (int gi = 0; gi < NGRP; ++gi)
            if (!((gmask >> gi) & 1) && gv[gi] > best) { best = gv[gi]; bi = gi; }
        const int sel2 = bi; gmask |= 1 << bi;
        const float g3v = best;
        float g4v = -1e30f;
#pragma unroll
        for (int gi = 0; gi < NGRP; ++gi)
            if (!((gmask >> gi) & 1)) g4v = fmaxf(g4v, gv[gi]);
        float mall = gv[0];
#pragma unroll
        for (int gi = 1; gi < NGRP; ++gi) mall = fmaxf(mall, gv[gi]);

        float dsum = 0.f;
#pragma unroll
        for (int j = 0; j < EPG; ++j)
            dsum += expf(pL[(gl * EPG + j) * LPAD + t] - mall);
        dsum += __shfl_xor(dsum, 1);
        dsum += __shfl_xor(dsum, 2);
        dsum += __shfl_xor(dsum, 4);
        const float invd = 1.0f / dsum;

        float cvv[8]; int ce[8];
#pragma unroll
        for (int c = 0; c < 8; ++c) {
            const int i = gl + 8 * c;
            if (i < 60) {
                const int sgrp = (i >= 40) ? sel2 : ((i >= 20) ? sel1 : sel0);
                const int e = sgrp * EPG + (i - ((i >= 40) ? 40 : ((i >= 20) ? 20 : 0)));
                ce[c] = e;
                cvv[c] = pL[e * LPAD + t];
            } else { ce[c] = 999; cvv[c] = -1e30f; }
        }

        int ch0, ch1, ch2, ch3, ch4, ch5;
        float cv0, cv1, cv2, cv3, cv4, cv5, cv6;
#pragma unroll
        for (int p = 0; p < 7; ++p) {
            float bv = -1e30f; int be = 999;
#pragma unroll
            for (int c = 0; c < 8; ++c)
                if (cvv[c] > bv || (cvv[c] == bv && ce[c] < be)) { bv = cvv[c]; be = ce[c]; }
#pragma unroll
            for (int off = 1; off < 8; off <<= 1) {
                const float ov = __shfl_xor(bv, off);
                const int   oe = __shfl_xor(be, off);
                if (ov > bv || (ov == bv && oe < be)) { bv = ov; be = oe; }
            }
#pragma unroll
            for (int c = 0; c < 8; ++c) if (ce[c] == be) cvv[c] = -1e30f;
            if (p == 0) { ch0 = be; cv0 = bv; }
            else if (p == 1) { ch1 = be; cv1 = bv; }
            else if (p == 2) { ch2 = be; cv2 = bv; }
            else if (p == 3) { ch3 = be; cv3 = bv; }
            else if (p == 4) { ch4 = be; cv4 = bv; }
            else if (p == 5) { ch5 = be; cv5 = bv; }
            else { cv6 = bv; }
        }

        if (gl == 0) {
            const int gt = tokBase + t;
            out[(size_t)gt * KTOP + 0] = (float)ch0;
            out[(size_t)gt * KTOP + 1] = (float)ch1;
            out[(size_t)gt * KTOP + 2] = (float)ch2;
            out[(size_t)gt * KTOP + 3] = (float)ch3;
            out[(size_t)gt * KTOP + 4] = (float)ch4;
            out[(size_t)gt * KTOP + 5] = (float)ch5;
            float* wo = out + (size_t)T_TOKENS * KTOP + (size_t)gt * KTOP;
            wo[0] = expf(cv0 - mall) * invd * 16.0f;
            wo[1] = expf(cv1 - mall) * invd * 16.0f;
            wo[2] = expf(cv2 - mall) * invd * 16.0f;
            wo[3] = expf(cv3 - mall) * invd * 16.0f;
            wo[4] = expf(cv4 - mall) * invd * 16.0f;
            wo[5] = expf(cv5 - mall) * invd * 16.0f;
            atomicAdd(&histL[ch0], 1u); atomicAdd(&histL[ch1], 1u);
            atomicAdd(&histL[ch2], 1u); atomicAdd(&histL[ch3], 1u);
            atomicAdd(&histL[ch4], 1u); atomicAdd(&histL[ch5], 1u);
            m_arr[t] = mall; invd_arr[t] = invd;
            float mg2 = g3v - g4v;
            mg2 = fminf(mg2, cv0 - cv1); mg2 = fminf(mg2, cv1 - cv2);
            mg2 = fminf(mg2, cv2 - cv3); mg2 = fminf(mg2, cv3 - cv4);
            mg2 = fminf(mg2, cv4 - cv5); mg2 = fminf(mg2, cv5 - cv6);
            if (mg2 < 1e-4f) {
                const unsigned pos = atomicAdd(flagCnt, 1u);
                flagList[pos] = (unsigned)gt;
            }
        }
    }
    __syncthreads();

    if (tid < NEXP) {
        const float* Le = pL + tid * LPAD;
        float s = 0.f;
#pragma unroll 4
        for (int t0 = 0; t0 < 64; t0 += 4) {
            const float4 lv = *(const float4*)(Le + t0);
            const float4 mv = *(const float4*)(m_arr + t0);
            const float4 iv = *(const float4*)(invd_arr + t0);
            s += expf(lv.x - mv.x) * iv.x;
            s += expf(lv.y - mv.y) * iv.y;
            s += expf(lv.z - mv.z) * iv.z;
            s += expf(lv.w - mv.w) * iv.w;
        }
        piPart[(size_t)tid * NEPI + blockIdx.x]   = s;
        histPart[(size_t)tid * NEPI + blockIdx.x] = histL[tid];
    }
}

// ---- fp64 fixup: parallel dots + wave-parallel fp64 selection -----------------
__global__ __launch_bounds__(1024)
void moe_gate_fixup(const float* __restrict__ X, const float* __restrict__ W,
                    float* __restrict__ out, const unsigned int* __restrict__ flagCnt,
                    const unsigned int* __restrict__ flagList)
{
    __shared__ float xs[HID];
    __shared__ double ld[NEXP];
    const int nflag = (int)*flagCnt;
    const int tid = threadIdx.x;
    const int wv = tid >> 6, ln = tid & 63;   // 16 waves

    for (int i = blockIdx.x; i < nflag; i += gridDim.x) {
        const int t = (int)flagList[i];
        __syncthreads();
        for (int k = tid; k < HID / 4; k += 1024)
            ((float4*)xs)[k] = ((const float4*)(X + (size_t)t * HID))[k];
        __syncthreads();

#pragma unroll 1
        for (int e = wv; e < NEXP; e += 16) {
            const float* wr = W + (size_t)e * HID + ln * 4;
            const float* xp = xs + ln * 4;
            float4 w4[8];
#pragma unroll
            for (int j = 0; j < 8; ++j) w4[j] = *(const float4*)(wr + j * 256);
            double a0 = 0.0, a1 = 0.0;
#pragma unroll
            for (int j = 0; j < 8; ++j) {
                a0 = fma((double)xp[j * 256 + 0], (double)w4[j].x, a0);
                a1 = fma((double)xp[j * 256 + 1], (double)w4[j].y, a1);
                a0 = fma((double)xp[j * 256 + 2], (double)w4[j].z, a0);
                a1 = fma((double)xp[j * 256 + 3], (double)w4[j].w, a1);
            }
            double a = a0 + a1;
#pragma unroll
            for (int off = 32; off > 0; off >>= 1) a += __shfl_down(a, off);
            if (ln == 0) ld[e] = a;
        }
        __syncthreads();

        if (wv == 0) {
            const int gl = ln & 7;
            const int lbase = ln & 0x38;

            double gm = ld[gl * EPG];
#pragma unroll
            for (int j = 1; j < EPG; ++j) {
                const double v = ld[gl * EPG + j];
                if (v > gm) gm = v;
            }
            double gv[8];
#pragma unroll
            for (int gi = 0; gi < 8; ++gi) gv[gi] = __shfl(gm, lbase + gi);

            double best = -1.0e300; int bi = 0;
#pragma unroll
            for (int gi = 0; gi < NGRP; ++gi)
                if (gv[gi] > best) { best = gv[gi]; bi = gi; }
            const int sel0 = bi; int gmask = 1 << bi;
            best = -1.0e300; bi = 0;
#pragma unroll
            for (int gi = 0; gi < NGRP; ++gi)
                if (!((gmask >> gi) & 1) && gv[gi] > best) { best = gv[gi]; bi = gi; }
            const int sel1 = bi; gmask |= 1 << bi;
            best = -1.0e300; bi = 0;
#pragma unroll
            for (int gi = 0; gi < NGRP; ++gi)
                if (!((gmask >> gi) & 1) && gv[gi] > best) { best = gv[gi]; bi = gi; }
            const int sel2 = bi; gmask |= 1 << bi;
            double mall = gv[0];
#pragma unroll
            for (int gi = 1; gi < NGRP; ++gi) if (gv[gi] > mall) mall = gv[gi];

            float dsum = 0.f;
#pragma unroll
            for (int j = 0; j < EPG; ++j)
                dsum += expf((float)(ld[gl * EPG + j] - mall));
            dsum += __shfl_xor(dsum, 1);
            dsum += __shfl_xor(dsum, 2);
            dsum += __shfl_xor(dsum, 4);
            const float invd = 1.0f / dsum;

            double cvv[8]; int ce[8];
#pragma unroll
            for (int c = 0; c < 8; ++c) {
                const int idx = gl + 8 * c;
                if (idx < 60) {
                    const int sgrp = (idx >= 40) ? sel2 : ((idx >= 20) ? sel1 : sel0);
                    const int e = sgrp * EPG + (idx - ((idx >= 40) ? 40 : ((idx >= 20) ? 20 : 0)));
                    ce[c] = e;
                    cvv[c] = ld[e];
                } else { ce[c] = 999; cvv[c] = -1.0e300; }
            }

#pragma unroll
            for (int p = 0; p < KTOP; ++p) {
                double bv = -1.0e300; int be = 999;
#pragma unroll
                for (int c = 0; c < 8; ++c)
                    if (cvv[c] > bv || (cvv[c] == bv && ce[c] < be)) { bv = cvv[c]; be = ce[c]; }
#pragma unroll
                for (int off = 1; off < 8; off <<= 1) {
                    const double ov = __shfl_xor(bv, off);
                    const int    oe = __shfl_xor(be, off);
                    if (ov > bv || (ov == bv && oe < be)) { bv = ov; be = oe; }
                }
#pragma unroll
                for (int c = 0; c < 8; ++c) if (ce[c] == be) cvv[c] = -1.0e300;
                if (ln == 0) {
                    out[(size_t)t * KTOP + p] = (float)be;
                    out[(size_t)T_TOKENS * KTOP + (size_t)t * KTOP + p] =
                        expf((float)(bv - mall)) * invd * 16.0f;
                }
            }
        }
        __syncthreads();
    }
}

// ---- aux loss: reduce partials ----------------------------------------------
__global__ __launch_bounds__(256)
void moe_gate_aux(const float* __restrict__ piPart,
                  const unsigned int* __restrict__ histPart,
                  float* __restrict__ out)
{
    __shared__ double buf[NEXP];
    const int tid = threadIdx.x;
    if (tid < NEXP) {
        const float* pp = piPart + (size_t)tid * NEPI;
        const unsigned int* hp = histPart + (size_t)tid * NEPI;
        float s = 0.f;
        unsigned c = 0;
#pragma unroll 8
        for (int b = 0; b < NEPI; ++b) { s += pp[b]; c += hp[b]; }
        buf[tid] = (double)s * (double)c;
    }
    __syncthreads();
    if (tid == 0) {
        double s = 0.0;
        for (int e = 0; e < NEXP; ++e) s += buf[e];
        const double aux = s * (0.001 * (double)NEXP) /
                           ((double)T_TOKENS * (double)T_TOKENS * (double)KTOP);
        out[(size_t)T_TOKENS * KTOP * 2] = (float)aux;
    }
}

extern "C" void kernel_launch(void* const* d_in, const int* in_sizes, int n_in,
                              void* d_out, int out_size, void* d_ws, size_t ws_size,
                              hipStream_t stream)
{
    const float* X = (const float*)d_in[0];   // [16384, 2048]
    const float* W = (const float*)d_in[1];   // [160, 2048]
    float* out = (float*)d_out;               // [98304 idx][98304 wgt][1 aux]

    char* ws = (char*)d_ws;
    short* wpk = (short*)ws;                                    // 1,310,720 B
    float* glog = (float*)(ws + 1310720);                       // 41,943,040 B
    float* piPart = (float*)(ws + 43253760);                    // 163,840 B
    unsigned int* histPart = (unsigned int*)(ws + 43417600);    // 163,840 B
    unsigned int* flagCnt  = (unsigned int*)(ws + 43581440);    // 16 B
    unsigned int* flagList = (unsigned int*)(ws + 43581456);    // 64 KB

    pack_w<<<160, 256, 0, stream>>>(W, wpk, flagCnt);
    moe_gemm<<<512, 512, 0, stream>>>(X, wpk, glog);
    moe_epi<<<NEPI, 512, 0, stream>>>(glog, out, piPart, histPart, flagCnt, flagList);
    moe_gate_fixup<<<512, 1024, 0, stream>>>(X, W, out, flagCnt, flagList);
    moe_gate_aux<<<1, 256, 0, stream>>>(piPart, histPart, out);
}